// Round 11
// baseline (640.465 us; speedup 1.0000x reference)
//
#include <hip/hip_runtime.h>
#include <cstdint>

typedef float  f32x4  __attribute__((ext_vector_type(4)));
typedef __bf16 bf16x8 __attribute__((ext_vector_type(8)));
typedef int    i32x4  __attribute__((ext_vector_type(4)));
typedef unsigned short u16;
typedef u16 u16x4 __attribute__((ext_vector_type(4)));

#define TT 512

// ---------- helpers ----------
__device__ __forceinline__ u16 f2bf(float f) {
  unsigned u = __builtin_bit_cast(unsigned, f);
  unsigned r = u + 0x7fffu + ((u >> 16) & 1u);   // RNE
  return (u16)(r >> 16);
}
__device__ __forceinline__ float bflo(unsigned d) { return __builtin_bit_cast(float, d << 16); }
__device__ __forceinline__ float bfhi(unsigned d) { return __builtin_bit_cast(float, d & 0xffff0000u); }
__device__ __forceinline__ float rcpf(float x) { return __builtin_amdgcn_rcpf(x); }
__device__ __forceinline__ float fsig(float x) { return rcpf(1.f + __expf(-x)); }
__device__ __forceinline__ float ftanh(float x) { return 1.f - 2.f * rcpf(1.f + __expf(2.f * x)); }

// ---------- single fused kernel (byte-identical resubmit of round 10;
// round-10 bench died with no pytest output = r6-style infra signature;
// structural audit found no r8-class hang mechanism -- see journal) ----------
// r9 finding: SQ_LDS_BANK_CONFLICT (12.58M) is bit-invariant under three
// different producer LDS layouts => it tracks the global_load_lds B-staging
// volume (constant 512KB/strip r3-r9), not the ds_read patterns. Producer is
// LDS-pipe-bound re-staging an L2-resident panel that never changes.
// Fix: NO B staging. prep writes Wx k-chunk-major (WxbKC[(kc*1024+col)*8])
// so B fragments load global->VGPR as 16-lane x 16B contiguous (256B blocks,
// L2-hot: 512KB/XCD). Bh buffers + 16 per-strip barriers GONE; inner 64
// ko-steps barrier-free. A keeps the r7-proven swizzle (r9 af regression
// reverted). Epilogue packing identical => xWp bit-identical => absmax canary
// 0.01171875. Consumer + sync protocol byte-identical r7. As padded to 82KB
// so LDS stays >80KB (HW-enforced 1 wg/CU co-residency).
__global__ __launch_bounds__(512, 2) void lstm_fused(
    const float* __restrict__ X,
    const float* __restrict__ wii, const float* __restrict__ whi,
    const float* __restrict__ wif, const float* __restrict__ whf,
    const float* __restrict__ wig, const float* __restrict__ whg,
    const float* __restrict__ wio, const float* __restrict__ who,
    const float* __restrict__ bii, const float* __restrict__ bhi,
    const float* __restrict__ bif, const float* __restrict__ bhf,
    const float* __restrict__ big_, const float* __restrict__ bhg,
    const float* __restrict__ bio, const float* __restrict__ bho,
    u16* __restrict__ WxbKC, signed char* __restrict__ Whq,
    float* __restrict__ wscale, float* __restrict__ bsum,
    u16* __restrict__ xWp, int* __restrict__ rprog, float* __restrict__ out) {
  __shared__ u16 As[164 * 256];                      // 82 KB (top 64KB used; pad keeps 1 wg/CU)
  __shared__ __align__(16) signed char hb[2][576];   // consumer
  int p = blockIdx.x;
  int tid = threadIdx.x;

  if (p >= 128) {
    // ================= producer =================
    int k = p - 128;

    // ---- in-kernel prep: cols k*8..k*8+7 of Wx (k-chunk-major) and Wh ----
    {
      int cl = tid >> 6, dl = tid & 63;   // col-local (wave id), d-lane
      int C = k * 8 + cl;                 // 0..1023
      int G = C >> 8, h = C & 255;
      const float* wxp[4] = {wii, wif, wig, wio};
      const float* whp[4] = {whi, whf, whg, who};
      const float* sx = wxp[G];
#pragma unroll
      for (int i = 0; i < 4; ++i) {
        int d = i * 64 + dl;
        // WxbKC[(kc*1024 + C)*8 + (d&7)], kc = d>>3
        WxbKC[((size_t)(i * 8 + (dl >> 3)) * 1024 + C) * 8 + (dl & 7)] =
            f2bf(sx[(size_t)d * 256 + h]);
      }
      const float* sh = whp[G];
      float wv[4];
      float am = 0.f;
#pragma unroll
      for (int i = 0; i < 4; ++i) {
        int d = i * 64 + dl;
        wv[i] = sh[(size_t)d * 256 + h];
        am = fmaxf(am, fabsf(wv[i]));
      }
#pragma unroll
      for (int off = 32; off > 0; off >>= 1)
        am = fmaxf(am, __shfl_xor(am, off, 64));
      float scale = (am > 0.f) ? am * (1.f / 127.f) : 1.f;
      if (dl == 0) wscale[C] = scale * (1.f / 127.f);   // combined w*h scale
#pragma unroll
      for (int i = 0; i < 4; ++i) {
        float qf = rintf(wv[i] / scale);
        qf = fminf(127.f, fmaxf(-127.f, qf));
        Whq[(size_t)C * 256 + i * 64 + dl] = (signed char)(int)qf;
      }
      if (k == 0 && tid < 256) {
        const float* bx[4] = {bii, bif, big_, bio};
        const float* bh4[4] = {bhi, bhf, bhg, bho};
        for (int Gg = 0; Gg < 4; ++Gg) bsum[Gg * 256 + tid] = bx[Gg][tid] + bh4[Gg][tid];
      }
      __syncthreads();                    // drain all waves' stores (vmcnt0)
      if (tid == 0)
        __hip_atomic_fetch_add(&rprog[8], 1, __ATOMIC_RELEASE, __HIP_MEMORY_SCOPE_AGENT);
      if (tid == 0) {
        while (__hip_atomic_load(&rprog[8], __ATOMIC_RELAXED, __HIP_MEMORY_SCOPE_AGENT) < 128)
          __builtin_amdgcn_s_sleep(8);
        (void)__hip_atomic_load(&rprog[8], __ATOMIC_ACQUIRE, __HIP_MEMORY_SCOPE_AGENT);
      }
      __syncthreads();                    // all prep visible; WxbKC/bsum readable
    }

    int l = tid & 63, w8 = tid >> 6;
    int wm = w8 >> 2, wn = w8 & 3;                   // 2 row-halves x 4 col-quads
    int c = l & 15, q = l >> 4;
    int sw = (c & 7) << 4;
    int rowbase[4];
#pragma unroll
    for (int mt = 0; mt < 4; ++mt) rowbase[mt] = (wm * 64 + mt * 16 + c) * 512;

    for (int j = 0; j < 8; ++j) {
      int bm = j * 128 + k;
      __syncthreads();                               // As free (prev strip fully read)
      // stage A strip: 128 rows x 256 k, f32 -> bf16, XOR-swizzled (r7-proven)
#pragma unroll 4
      for (int jj = 0; jj < 16; ++jj) {
        int row_l = jj * 8 + w8;                     // wave reads one row contiguously
        int d = l * 4;
        int r = bm * 128 + row_l;
        int t = r >> 8, n = r & 255;
        const float4 v = *(const float4*)(X + ((size_t)n * 512 + t) * 256 + d);
        u16x4 pk;
        pk[0] = f2bf(v.x); pk[1] = f2bf(v.y); pk[2] = f2bf(v.z); pk[3] = f2bf(v.w);
        int ba = (row_l * 512 + l * 8) ^ ((row_l & 7) << 4);
        *(u16x4*)((char*)As + ba) = pk;
      }
      __syncthreads();                               // A ready

      f32x4 acc[4][2];
#pragma unroll
      for (int i = 0; i < 4; ++i)
#pragma unroll
        for (int jn = 0; jn < 2; ++jn) acc[i][jn] = (f32x4){0.f, 0.f, 0.f, 0.f};

      for (int bn = 0; bn < 8; ++bn) {
        // B base for this wave: col = bn*128 + wn*32 + c, kc = ko*4 + q
        const u16* bsrc0 = WxbKC + (size_t)q * 8192 + (bn * 128 + wn * 32 + c) * 8;
#pragma unroll
        for (int ko = 0; ko < 8; ++ko) {             // barrier-free inner loop
          bf16x8 af[4], bfr[2];
          int koff = (ko * 64 + q * 16) ^ sw;        // A involution (r7 layout)
#pragma unroll
          for (int mt = 0; mt < 4; ++mt)
            af[mt] = *(const bf16x8*)((const char*)As + rowbase[mt] + koff);
          const u16* bsrc = bsrc0 + (size_t)ko * 32768;   // kc += 4 per ko
          bfr[0] = *(const bf16x8*)(bsrc);           // nt=0
          bfr[1] = *(const bf16x8*)(bsrc + 128);     // nt=1 (col+16 -> +128 u16)
#pragma unroll
          for (int mt = 0; mt < 4; ++mt)
#pragma unroll
            for (int nt = 0; nt < 2; ++nt)
              acc[mt][nt] = __builtin_amdgcn_mfma_f32_16x16x32_bf16(af[mt], bfr[nt], acc[mt][nt], 0, 0, 0);
        }
        // epilogue for bn (identical packing to verified kernel)
#pragma unroll
        for (int mt = 0; mt < 4; ++mt) {
          int tm = bm * 8 + wm * 4 + mt;
#pragma unroll
          for (int nt = 0; nt < 2; ++nt) {
            int tn = bn * 8 + wn * 2 + nt;
            float bv = bsum[tn * 16 + c];
            u16x4 pk;
#pragma unroll
            for (int r = 0; r < 4; ++r) pk[r] = f2bf(acc[mt][nt][r] + bv);
            *reinterpret_cast<u16x4*>(xWp + ((size_t)(tm * 64 + tn) * 256 + l * 4)) = pk;
            acc[mt][nt] = (f32x4){0.f, 0.f, 0.f, 0.f};
          }
        }
      }
      __syncthreads();                  // all waves done (stores drained, As read done)
      if (tid == 0)
        __hip_atomic_fetch_add(&rprog[j], 1, __ATOMIC_RELEASE, __HIP_MEMORY_SCOPE_AGENT);
    }
    return;
  }

  // ================= consumer (verified lstm_rec + waits; r7 byte-identical) =================
  int xcd = p & 7, q8 = (p >> 3) & 7, tsel = p >> 6;
  int G = xcd * 2 + tsel;        // 16-row tile id; 8 co-XCD sharers
  int wid = tid >> 6, l = tid & 63;
  int c = l & 15, q = (l >> 4) & 3;
  int tt = q >> 1, rsel = q & 1;

  for (int i = tid; i < 288; i += 512) ((int*)hb)[i] = 0;

  // wait for in-kernel prep (Whq/wscale valid) before fragment loads
  if (tid == 0) {
    while (__hip_atomic_load(&rprog[8], __ATOMIC_RELAXED, __HIP_MEMORY_SCOPE_AGENT) < 128)
      __builtin_amdgcn_s_sleep(8);
    (void)__hip_atomic_load(&rprog[8], __ATOMIC_ACQUIRE, __HIP_MEMORY_SCOPE_AGENT);
  }
  __syncthreads();

  // Wh i8 fragments: [gate][tt-tile][kstep] -> forced into AGPRs by asm "a" use
  i32x4 bw[4][2][4];
#pragma unroll
  for (int g = 0; g < 4; ++g)
#pragma unroll
    for (int ttl = 0; ttl < 2; ++ttl) {
      int col = g * 256 + wid * 32 + ttl * 16 + c;
#pragma unroll
      for (int ks = 0; ks < 4; ++ks)
        bw[g][ttl][ks] = *reinterpret_cast<const i32x4*>(Whq + (size_t)col * 256 + ks * 64 + q * 16);
    }
  float sc8[4];
#pragma unroll
  for (int g = 0; g < 4; ++g) sc8[g] = wscale[g * 256 + wid * 32 + tt * 16 + c];

  // xW: tile tm = t*16 + G; this wg's rows are regs {2*(q8&1), +1} of quad q8>>1
  const char* xbase = (const char*)xWp + (size_t)G * 32768;
  int xoff[4];
#pragma unroll
  for (int g = 0; g < 4; ++g) {
    int tn = g * 16 + wid * 2 + tt;
    xoff[g] = tn * 512 + (((q8 >> 1) * 16 + c) * 8) + (q8 & 1) * 4;
  }

  // wait for round 0 (t=0..63) before touching xWp
  if (tid == 0) {
    while (__hip_atomic_load(&rprog[0], __ATOMIC_RELAXED, __HIP_MEMORY_SCOPE_AGENT) < 128)
      __builtin_amdgcn_s_sleep(8);
    (void)__hip_atomic_load(&rprog[0], __ATOMIC_ACQUIRE, __HIP_MEMORY_SCOPE_AGENT);
  }
  __syncthreads();

  unsigned xw0[4], xw1[4];
#pragma unroll
  for (int g = 0; g < 4; ++g) xw0[g] = *(const unsigned*)(xbase + xoff[g]);   // t=0
  xbase += 524288;   // -> t=1

  i32x4 zacc = (i32x4){0, 0, 0, 0};
  float cs = 0.f, hh = 0.f;
  __syncthreads();

#define STEP(CUR, XW_CUR, XW_NXT)                                               \
  {                                                                             \
    _Pragma("unroll")                                                           \
    for (int g = 0; g < 4; ++g) XW_NXT[g] = *(const unsigned*)(xbase + xoff[g]);\
    const signed char* hr = hb[CUR ^ 1];                                        \
    i32x4 acc[4][2];                                                            \
    {                                                                           \
      i32x4 a0 = *(const i32x4*)(hr + (c & 1) * 288 + q * 16);                  \
      _Pragma("unroll")                                                         \
      for (int g = 0; g < 4; ++g) {                                             \
        __asm__("v_mfma_i32_16x16x64_i8 %0, %1, %2, %3"                         \
                : "=&v"(acc[g][0]) : "v"(a0), "a"(bw[g][0][0]), "v"(zacc));     \
        __asm__("v_mfma_i32_16x16x64_i8 %0, %1, %2, %3"                         \
                : "=&v"(acc[g][1]) : "v"(a0), "a"(bw[g][1][0]), "v"(zacc));     \
      }                                                                         \
    }                                                                           \
    _Pragma("unroll")                                                           \
    for (int ks = 1; ks < 4; ++ks) {                                            \
      i32x4 a = *(const i32x4*)(hr + (c & 1) * 288 + ks * 64 + q * 16);         \
      _Pragma("unroll")                                                         \
      for (int g = 0; g < 4; ++g) {                                             \
        __asm__("v_mfma_i32_16x16x64_i8 %0, %1, %2, %0"                         \
                : "+v"(acc[g][0]) : "v"(a), "a"(bw[g][0][ks]));                 \
        __asm__("v_mfma_i32_16x16x64_i8 %0, %1, %2, %0"                         \
                : "+v"(acc[g][1]) : "v"(a), "a"(bw[g][1][ks]));                 \
      }                                                                         \
    }                                                                           \
    __asm__ volatile("s_nop 7\n\ts_nop 7\n\ts_nop 7");  /* MFMA->VALU hazard */ \
    float a4[4];                                                                \
    _Pragma("unroll")                                                           \
    for (int g = 0; g < 4; ++g) {                                               \
      int e = tt ? (rsel ? acc[g][1][1] : acc[g][1][0])                         \
                 : (rsel ? acc[g][0][1] : acc[g][0][0]);                        \
      unsigned d = XW_CUR[g];                                                   \
      float xv = rsel ? bfhi(d) : bflo(d);                                      \
      a4[g] = (float)e * sc8[g] + xv;                                           \
    }                                                                           \
    float gi = fsig(a4[0]);                                                     \
    float gf = fsig(a4[1]);                                                     \
    float gg = ftanh(a4[2]);                                                    \
    float go = fsig(a4[3]);                                                     \
    cs = gf * cs + gi * gg;                                                     \
    hh = go * ftanh(cs);                                                        \
    int hq = (int)rintf(hh * 127.f);                                            \
    hb[CUR][rsel * 288 + wid * 32 + tt * 16 + c] = (signed char)hq;             \
    xbase += 524288;                                                            \
    __builtin_amdgcn_s_waitcnt(0xC07F);  /* lgkmcnt(0) only, vmcnt in flight */ \
    __builtin_amdgcn_s_barrier();                                               \
  }

  for (int t = 0; t < TT; t += 2) {
    STEP(0, xw0, xw1)
    if (((t + 2) & 63) == 0 && (t + 2) < TT) {
      // next STEP prefetches t+2 (first step of round (t+2)/64): wait for it
      int j = (t + 2) >> 6;
      if (tid == 0) {
        while (__hip_atomic_load(&rprog[j], __ATOMIC_RELAXED, __HIP_MEMORY_SCOPE_AGENT) < 128)
          __builtin_amdgcn_s_sleep(8);
        (void)__hip_atomic_load(&rprog[j], __ATOMIC_ACQUIRE, __HIP_MEMORY_SCOPE_AGENT);
      }
      __syncthreads();
    }
    STEP(1, xw1, xw0)
  }
#undef STEP

  {
    int n = G * 16 + q8 * 2 + rsel;
    int hu = wid * 32 + tt * 16 + c;
    out[(size_t)n * 256 + hu] = hh;
    out[65536 + (size_t)n * 256 + hu] = cs;
  }
}

// ---------- launch ----------
extern "C" void kernel_launch(void* const* d_in, const int* in_sizes, int n_in,
                              void* d_out, int out_size, void* d_ws, size_t ws_size,
                              hipStream_t stream) {
  const float* x   = (const float*)d_in[0];
  const float* wii = (const float*)d_in[1];
  const float* whi = (const float*)d_in[2];
  const float* wif = (const float*)d_in[3];
  const float* whf = (const float*)d_in[4];
  const float* wig = (const float*)d_in[5];
  const float* whg = (const float*)d_in[6];
  const float* wio = (const float*)d_in[7];
  const float* who = (const float*)d_in[8];
  const float* bii = (const float*)d_in[9];
  const float* bhi = (const float*)d_in[10];
  const float* bif = (const float*)d_in[11];
  const float* bhf = (const float*)d_in[12];
  const float* big_ = (const float*)d_in[13];
  const float* bhg = (const float*)d_in[14];
  const float* bio = (const float*)d_in[15];
  const float* bho = (const float*)d_in[16];

  char* ws = (char*)d_ws;
  int*   rprog  = (int*)(ws);                         // [0..7] rounds, [8] prep
  u16*   WxbKC  = (u16*)(ws + 67108864);              //    524,288 B (k-chunk-major)
  signed char* Whq = (signed char*)(ws + 67633152);   //    262,144 B
  float* wscale = (float*)(ws + 67895296);            //      4,096 B
  float* bsum   = (float*)(ws + 67899392);            //      4,096 B
  u16*   xWp    = (u16*)(ws + 67903488);              // 268,435,456 B + pad
  float* out = (float*)d_out;

  hipMemsetAsync(rprog, 0, 64, stream);
  lstm_fused<<<256, 512, 0, stream>>>(x,
                                      wii, whi, wif, whf, wig, whg, wio, who,
                                      bii, bhi, bif, bhf, big_, bhg, bio, bho,
                                      WxbKC, Whq, wscale, bsum, xWp, rprog, out);
}